// Round 2
// 1603.929 us; speedup vs baseline: 1.7207x; 1.7207x over previous
//
#include <hip/hip_runtime.h>
#include <cstdint>
#include <cstddef>

#define N_AREA 10000
#define N_FEAT 16
#define HID 64
#define BATCH 64
#define EPSL 1e-5f
#define SLOPE 0.01f
#define NCHUNK 157  // ceil(10000/64)

__device__ __forceinline__ float lrelu(float x) { return x >= 0.f ? x : SLOPE * x; }
__device__ __forceinline__ float tanh_fast(float x) {
    float t = __expf(2.0f * x);  // v_exp_f32 path
    return 1.0f - 2.0f / (t + 1.0f);
}

__global__ __launch_bounds__(256) void k_zero(int* p, int n) {
    int i = blockIdx.x * 256 + threadIdx.x;
    if (i < n) p[i] = 0;
}

__global__ __launch_bounds__(256) void k_hist(const int* __restrict__ dst, int* __restrict__ counts, int E) {
    int e = blockIdx.x * 256 + threadIdx.x;
    if (e < E) atomicAdd(&counts[dst[e]], 1);
}

// offsets (exclusive, +1 self-loop slot), dinv, self-loop entry, cursor init.
__global__ __launch_bounds__(1024) void k_scan(const int* __restrict__ counts, int* __restrict__ offsets,
                                               int* __restrict__ cursor, float* __restrict__ dinv,
                                               int2* __restrict__ ew) {
    const int PER = 10;
    int t = threadIdx.x;
    int base = t * PER;
    int local[PER];
    int sum = 0;
#pragma unroll
    for (int i = 0; i < PER; ++i) {
        int idx = base + i;
        int c = (idx < N_AREA) ? (counts[idx] + 1) : 0;
        local[i] = sum;
        sum += c;
    }
    __shared__ int part[1024];
    part[t] = sum;
    __syncthreads();
    for (int off = 1; off < 1024; off <<= 1) {
        int v = (t >= off) ? part[t - off] : 0;
        __syncthreads();
        part[t] += v;
        __syncthreads();
    }
    int excl = (t == 0) ? 0 : part[t - 1];
    if (t == 1023) offsets[N_AREA] = part[1023];
    for (int i = 0; i < PER; ++i) {
        int idx = base + i;
        if (idx < N_AREA) {
            int off = excl + local[i];
            offsets[idx] = off;
            float dv = rsqrtf((float)(counts[idx] + 1));
            dinv[idx] = dv;
            ew[off] = make_int2(idx, __float_as_int(dv * dv));  // self loop
            cursor[idx] = off + 1;
        }
    }
}

__global__ __launch_bounds__(256) void k_scatter(const int* __restrict__ ei, const float* __restrict__ dinv,
                                                 int* __restrict__ cursor, int2* __restrict__ ew, int E) {
    int e = blockIdx.x * 256 + threadIdx.x;
    if (e < E) {
        int s = ei[e], d = ei[E + e];
        int p = atomicAdd(&cursor[d], 1);
        ew[p] = make_int2(s, __float_as_int(dinv[s] * dinv[d]));
    }
}

// conv1 fused: gather(state rows of 16) -> @W1+b1 -> LN -> leaky -> h1 [B][N][64]
__global__ __launch_bounds__(256, 8) void k_conv1(const float* __restrict__ state, const float* __restrict__ W1,
                                                  const float* __restrict__ b1, const float* __restrict__ g1,
                                                  const float* __restrict__ be1, float* __restrict__ h1,
                                                  const int* __restrict__ offs, const int2* __restrict__ ew) {
    __shared__ float xs[64][20];  // padded: node stride 20 floats keeps b128 aligned + banks spread
    __shared__ float ws[16][64];
    int blk = blockIdx.x;
    int xc = blk & 7, ii = blk >> 3;  // XCD group: batch b on XCD b%8
    int b = xc + 8 * (ii / NCHUNK);
    int c = ii % NCHUNK;
    int n0 = c * 64;
    int t = threadIdx.x;
    *(float4*)&ws[t >> 4][(t & 15) * 4] = *(const float4*)(W1 + (t >> 4) * HID + (t & 15) * 4);
    int ln = t >> 2, q = t & 3;
    int n = n0 + ln;
    const float* sb = state + (size_t)b * (N_AREA * N_FEAT);
    float4 acc = make_float4(0.f, 0.f, 0.f, 0.f);
    if (n < N_AREA) {
        int beg = offs[n], end = offs[n + 1];
        for (int e = beg; e < end; ++e) {
            int2 sw = ew[e];
            float w = __int_as_float(sw.y);
            float4 v = *(const float4*)(sb + (size_t)sw.x * N_FEAT + q * 4);
            acc.x += w * v.x; acc.y += w * v.y; acc.z += w * v.z; acc.w += w * v.w;
        }
    }
    *(float4*)&xs[ln][q * 4] = acc;
    __syncthreads();
    int wave = t >> 6, lane = t & 63;
    float bias = b1[lane], gg = g1[lane], bb = be1[lane];
    for (int j = 0; j < 16; ++j) {
        int lnn = wave * 16 + j;
        float a = bias;
#pragma unroll
        for (int f = 0; f < N_FEAT; ++f) a += xs[lnn][f] * ws[f][lane];
        float s = a;
#pragma unroll
        for (int m = 1; m < 64; m <<= 1) s += __shfl_xor(s, m);
        float mu = s * (1.0f / 64.0f);
        float dv = a - mu;
        float qv = dv * dv;
#pragma unroll
        for (int m = 1; m < 64; m <<= 1) qv += __shfl_xor(qv, m);
        float rstd = rsqrtf(qv * (1.0f / 64.0f) + EPSL);
        float y = lrelu(dv * rstd * gg + bb);
        int nn = n0 + lnn;
        if (nn < N_AREA) h1[(size_t)b * (N_AREA * HID) + (size_t)nn * HID + lane] = y;
    }
}

// Fused conv: wave-uniform gather (scalar edge loads) into LDS -> 64x64 GEMM (W from L1) -> epilogue
// EPI 0: out = leaky(.+b) + resid
// EPI 2: h3 = leaky(LN(.+b)) + resid; out = tanh(h3 @ Wf + bf)   (fuses final GEMM, no h3 round-trip)
template <int EPI>
__global__ __launch_bounds__(256, 8) void k_conv(const float* __restrict__ src, const float* __restrict__ W,
                                                 const float* __restrict__ bias, const float* __restrict__ g,
                                                 const float* __restrict__ be, const float* __restrict__ resid,
                                                 float* __restrict__ out, const int* __restrict__ offs,
                                                 const int2* __restrict__ ew, const float* __restrict__ Wf,
                                                 const float* __restrict__ bf) {
    __shared__ float a_t[64][68];  // [feat][node] for GEMM1; reused as [node][feat] for fused GEMM2
    int blk = blockIdx.x;
    int xc = blk & 7, ii = blk >> 3;
    int b = xc + 8 * (ii / NCHUNK);
    int c = ii % NCHUNK;
    int n0 = c * 64;
    int t = threadIdx.x;
    int lane = t & 63;
    int wave = __builtin_amdgcn_readfirstlane(t) >> 6;  // provably wave-uniform -> scalar edge loads
    const float* sb = src + (size_t)b * (N_AREA * HID);
    for (int j = 0; j < 16; ++j) {
        int ln = wave * 16 + j;   // uniform
        int n = n0 + ln;          // uniform
        float acc = 0.f;
        if (n < N_AREA) {
            int beg = offs[n], end = offs[n + 1];  // s_load
            int e = beg;
            for (; e + 3 < end; e += 4) {
                int2 e0 = ew[e], e1 = ew[e + 1], e2 = ew[e + 2], e3 = ew[e + 3];  // s_load_dwordx8
                acc += __int_as_float(e0.y) * (sb + (unsigned)e0.x * HID)[lane];
                acc += __int_as_float(e1.y) * (sb + (unsigned)e1.x * HID)[lane];
                acc += __int_as_float(e2.y) * (sb + (unsigned)e2.x * HID)[lane];
                acc += __int_as_float(e3.y) * (sb + (unsigned)e3.x * HID)[lane];
            }
            for (; e < end; ++e) {
                int2 e0 = ew[e];
                acc += __int_as_float(e0.y) * (sb + (unsigned)e0.x * HID)[lane];
            }
        }
        a_t[lane][ln] = acc;
    }
    __syncthreads();
    int ty = t >> 4, tx = t & 15;
    int r0 = ty * 4, c0 = tx * 4;
    float am[4][4] = {};
#pragma unroll 4
    for (int k = 0; k < 64; ++k) {
        float4 av = *(const float4*)&a_t[k][r0];
        float4 wv = *(const float4*)(W + k * HID + c0);  // 16 KB, L1-resident, shared by all blocks
        am[0][0] += av.x * wv.x; am[0][1] += av.x * wv.y; am[0][2] += av.x * wv.z; am[0][3] += av.x * wv.w;
        am[1][0] += av.y * wv.x; am[1][1] += av.y * wv.y; am[1][2] += av.y * wv.z; am[1][3] += av.y * wv.w;
        am[2][0] += av.z * wv.x; am[2][1] += av.z * wv.y; am[2][2] += av.z * wv.z; am[2][3] += av.z * wv.w;
        am[3][0] += av.w * wv.x; am[3][1] += av.w * wv.y; am[3][2] += av.w * wv.z; am[3][3] += av.w * wv.w;
    }
    float4 bv = *(const float4*)(bias + c0);
#pragma unroll
    for (int i = 0; i < 4; ++i) {
        am[i][0] += bv.x; am[i][1] += bv.y; am[i][2] += bv.z; am[i][3] += bv.w;
    }
    if constexpr (EPI >= 1) {  // LayerNorm across 64 feats (feats live on the 16-thread tx group)
        float4 gv = *(const float4*)(g + c0);
        float4 bev = *(const float4*)(be + c0);
        float gg[4] = {gv.x, gv.y, gv.z, gv.w};
        float bb[4] = {bev.x, bev.y, bev.z, bev.w};
#pragma unroll
        for (int i = 0; i < 4; ++i) {
            float s = am[i][0] + am[i][1] + am[i][2] + am[i][3];
            float qv = am[i][0] * am[i][0] + am[i][1] * am[i][1] + am[i][2] * am[i][2] + am[i][3] * am[i][3];
#pragma unroll
            for (int m = 1; m < 16; m <<= 1) {
                s += __shfl_xor(s, m);
                qv += __shfl_xor(qv, m);
            }
            float mu = s * (1.0f / 64.0f);
            float var = qv * (1.0f / 64.0f) - mu * mu;
            float rstd = rsqrtf(var + EPSL);
#pragma unroll
            for (int j = 0; j < 4; ++j) am[i][j] = (am[i][j] - mu) * rstd * gg[j] + bb[j];
        }
    }
    const float* rb = resid + (size_t)b * (N_AREA * HID);
    float* ob = out + (size_t)b * (N_AREA * HID);
    if constexpr (EPI == 0) {
#pragma unroll
        for (int i = 0; i < 4; ++i) {
            int n = n0 + r0 + i;
            if (n < N_AREA) {
                float4 rv = *(const float4*)(rb + (size_t)n * HID + c0);
                float4 o;
                o.x = lrelu(am[i][0]) + rv.x;
                o.y = lrelu(am[i][1]) + rv.y;
                o.z = lrelu(am[i][2]) + rv.z;
                o.w = lrelu(am[i][3]) + rv.w;
                *(float4*)(ob + (size_t)n * HID + c0) = o;
            }
        }
    } else {  // EPI == 2: finish h3 in-register, stash tile to LDS, GEMM2 with Wf, tanh, store
#pragma unroll
        for (int i = 0; i < 4; ++i) {
            int n = n0 + r0 + i;
            int nc = n < N_AREA ? n : (N_AREA - 1);  // clamp OOB rows (values unused)
            float4 rv = *(const float4*)(rb + (size_t)nc * HID + c0);
            am[i][0] = lrelu(am[i][0]) + rv.x;
            am[i][1] = lrelu(am[i][1]) + rv.y;
            am[i][2] = lrelu(am[i][2]) + rv.z;
            am[i][3] = lrelu(am[i][3]) + rv.w;
        }
        __syncthreads();  // all GEMM1 reads of a_t done
        float (*h3s)[68] = a_t;  // reuse as [node][feat]
#pragma unroll
        for (int i = 0; i < 4; ++i)
            *(float4*)&h3s[r0 + i][c0] = make_float4(am[i][0], am[i][1], am[i][2], am[i][3]);
        __syncthreads();
#pragma unroll
        for (int i = 0; i < 4; ++i) { am[i][0] = 0.f; am[i][1] = 0.f; am[i][2] = 0.f; am[i][3] = 0.f; }
#pragma unroll 4
        for (int k = 0; k < 64; ++k) {
            float4 wv = *(const float4*)(Wf + k * HID + c0);
            float a0 = h3s[r0 + 0][k];  // 4 distinct addrs per wave -> broadcast, conflict-free
            float a1 = h3s[r0 + 1][k];
            float a2 = h3s[r0 + 2][k];
            float a3 = h3s[r0 + 3][k];
            am[0][0] += a0 * wv.x; am[0][1] += a0 * wv.y; am[0][2] += a0 * wv.z; am[0][3] += a0 * wv.w;
            am[1][0] += a1 * wv.x; am[1][1] += a1 * wv.y; am[1][2] += a1 * wv.z; am[1][3] += a1 * wv.w;
            am[2][0] += a2 * wv.x; am[2][1] += a2 * wv.y; am[2][2] += a2 * wv.z; am[2][3] += a2 * wv.w;
            am[3][0] += a3 * wv.x; am[3][1] += a3 * wv.y; am[3][2] += a3 * wv.z; am[3][3] += a3 * wv.w;
        }
        float4 bfv = *(const float4*)(bf + c0);
#pragma unroll
        for (int i = 0; i < 4; ++i) {
            int n = n0 + r0 + i;
            if (n < N_AREA) {
                float4 o;
                o.x = tanh_fast(am[i][0] + bfv.x);
                o.y = tanh_fast(am[i][1] + bfv.y);
                o.z = tanh_fast(am[i][2] + bfv.z);
                o.w = tanh_fast(am[i][3] + bfv.w);
                *(float4*)(ob + (size_t)n * HID + c0) = o;
            }
        }
    }
}

extern "C" void kernel_launch(void* const* d_in, const int* in_sizes, int n_in,
                              void* d_out, int out_size, void* d_ws, size_t ws_size,
                              hipStream_t stream) {
    const float* state = (const float*)d_in[0];
    const int* ei = (const int*)d_in[1];
    const int E = in_sizes[1] / 2;
    const float* W1 = (const float*)d_in[5];
    const float* b1 = (const float*)d_in[6];
    const float* W2 = (const float*)d_in[7];
    const float* b2 = (const float*)d_in[8];
    const float* W3 = (const float*)d_in[9];
    const float* b3 = (const float*)d_in[10];
    const float* g1 = (const float*)d_in[11];
    const float* be1 = (const float*)d_in[12];
    const float* g3 = (const float*)d_in[13];
    const float* be3 = (const float*)d_in[14];
    const float* Wf = (const float*)d_in[15];
    const float* bf = (const float*)d_in[16];
    float* out = (float*)d_out;

    uint8_t* base = (uint8_t*)d_ws;
    size_t off = 0;
    auto carve = [&](size_t bytes) {
        void* p = base + off;
        off = (off + bytes + 255) & ~(size_t)255;
        return p;
    };
    float* dinv = (float*)carve(N_AREA * 4);
    int* counts = (int*)carve(N_AREA * 4);
    int* offsets = (int*)carve((N_AREA + 1) * 4);
    int* cursor = (int*)carve(N_AREA * 4);
    int2* ew = (int2*)carve((size_t)(E + N_AREA) * 8);
    float* h1 = (float*)carve((size_t)BATCH * N_AREA * HID * 4);
    float* h2 = (float*)carve((size_t)BATCH * N_AREA * HID * 4);

    const int GRID = 8 * NCHUNK * (BATCH / 8);  // 10048

    k_zero<<<(N_AREA + 255) / 256, 256, 0, stream>>>(counts, N_AREA);
    k_hist<<<(E + 255) / 256, 256, 0, stream>>>(ei + E, counts, E);
    k_scan<<<1, 1024, 0, stream>>>(counts, offsets, cursor, dinv, ew);
    k_scatter<<<(E + 255) / 256, 256, 0, stream>>>(ei, dinv, cursor, ew, E);

    k_conv1<<<GRID, 256, 0, stream>>>(state, W1, b1, g1, be1, h1, offsets, ew);
    k_conv<0><<<GRID, 256, 0, stream>>>(h1, W2, b2, nullptr, nullptr, h1, h2, offsets, ew, nullptr, nullptr);
    k_conv<2><<<GRID, 256, 0, stream>>>(h2, W3, b3, g3, be3, h1, out, offsets, ew, Wf, bf);
}

// Round 3
// 1540.227 us; speedup vs baseline: 1.7918x; 1.0414x over previous
//
#include <hip/hip_runtime.h>
#include <cstdint>
#include <cstddef>

#define N_AREA 10000
#define N_FEAT 16
#define HID 64
#define BATCH 64
#define EPSL 1e-5f
#define SLOPE 0.01f
#define NCHUNK 157  // ceil(10000/64)

__device__ __forceinline__ float lrelu(float x) { return x >= 0.f ? x : SLOPE * x; }
__device__ __forceinline__ float tanh_fast(float x) {
    float t = __expf(2.0f * x);  // v_exp_f32 path
    return 1.0f - 2.0f / (t + 1.0f);
}

__global__ __launch_bounds__(256) void k_zero(int* p, int n) {
    int i = blockIdx.x * 256 + threadIdx.x;
    if (i < n) p[i] = 0;
}

__global__ __launch_bounds__(256) void k_hist(const int* __restrict__ dst, int* __restrict__ counts, int E) {
    int e = blockIdx.x * 256 + threadIdx.x;
    if (e < E) atomicAdd(&counts[dst[e]], 1);
}

// offsets (exclusive, padded to x4 per node: 1 self-loop + real edges + weight-0 pads),
// dinv, self-loop entry, pad entries, cursor init.
__global__ __launch_bounds__(1024) void k_scan(const int* __restrict__ counts, int* __restrict__ offsets,
                                               int* __restrict__ cursor, float* __restrict__ dinv,
                                               int2* __restrict__ ew) {
    const int PER = 10;
    int t = threadIdx.x;
    int base = t * PER;
    int local[PER];
    int sum = 0;
#pragma unroll
    for (int i = 0; i < PER; ++i) {
        int idx = base + i;
        int c = (idx < N_AREA) ? (((counts[idx] + 1) + 3) & ~3) : 0;  // padded count
        local[i] = sum;
        sum += c;
    }
    __shared__ int part[1024];
    part[t] = sum;
    __syncthreads();
    for (int off = 1; off < 1024; off <<= 1) {
        int v = (t >= off) ? part[t - off] : 0;
        __syncthreads();
        part[t] += v;
        __syncthreads();
    }
    int excl = (t == 0) ? 0 : part[t - 1];
    if (t == 1023) offsets[N_AREA] = part[1023];
    for (int i = 0; i < PER; ++i) {
        int idx = base + i;
        if (idx < N_AREA) {
            int off = excl + local[i];
            offsets[idx] = off;
            int c = counts[idx] + 1;          // real count (self + edges)
            int pc = (c + 3) & ~3;            // padded
            float dv = rsqrtf((float)c);
            dinv[idx] = dv;
            ew[off] = make_int2(idx, __float_as_int(dv * dv));  // self loop
            for (int pp = c; pp < pc; ++pp) ew[off + pp] = make_int2(idx, 0);  // weight-0 pads
            cursor[idx] = off + 1;
        }
    }
}

__global__ __launch_bounds__(256) void k_scatter(const int* __restrict__ ei, const float* __restrict__ dinv,
                                                 int* __restrict__ cursor, int2* __restrict__ ew, int E) {
    int e = blockIdx.x * 256 + threadIdx.x;
    if (e < E) {
        int s = ei[e], d = ei[E + e];
        int p = atomicAdd(&cursor[d], 1);
        ew[p] = make_int2(s, __float_as_int(dinv[s] * dinv[d]));
    }
}

// conv1 fused: gather(state rows of 16) -> @W1+b1 -> LN -> leaky -> h1 [B][N][64]
__global__ __launch_bounds__(256, 8) void k_conv1(const float* __restrict__ state, const float* __restrict__ W1,
                                                  const float* __restrict__ b1, const float* __restrict__ g1,
                                                  const float* __restrict__ be1, float* __restrict__ h1,
                                                  const int* __restrict__ offs, const int2* __restrict__ ew) {
    __shared__ float xs[64][20];  // padded: node stride 20 floats keeps b128 aligned + banks spread
    __shared__ float ws[16][64];
    int blk = blockIdx.x;
    int xc = blk & 7, ii = blk >> 3;  // XCD group: batch b on XCD b%8
    int b = xc + 8 * (ii / NCHUNK);
    int c = ii % NCHUNK;
    int n0 = c * 64;
    int t = threadIdx.x;
    *(float4*)&ws[t >> 4][(t & 15) * 4] = *(const float4*)(W1 + (t >> 4) * HID + (t & 15) * 4);
    int ln = t >> 2, q = t & 3;
    int n = n0 + ln;
    const float* sb = state + (size_t)b * (N_AREA * N_FEAT);
    float4 acc = make_float4(0.f, 0.f, 0.f, 0.f);
    if (n < N_AREA) {
        int beg = offs[n], end = offs[n + 1];
        for (int e = beg; e < end; ++e) {
            int2 sw = ew[e];
            float w = __int_as_float(sw.y);
            float4 v = *(const float4*)(sb + (size_t)sw.x * N_FEAT + q * 4);
            acc.x += w * v.x; acc.y += w * v.y; acc.z += w * v.z; acc.w += w * v.w;
        }
    }
    *(float4*)&xs[ln][q * 4] = acc;
    __syncthreads();
    int wave = t >> 6, lane = t & 63;
    float bias = b1[lane], gg = g1[lane], bb = be1[lane];
    for (int j = 0; j < 16; ++j) {
        int lnn = wave * 16 + j;
        float a = bias;
#pragma unroll
        for (int f = 0; f < N_FEAT; ++f) a += xs[lnn][f] * ws[f][lane];
        float s = a;
#pragma unroll
        for (int m = 1; m < 64; m <<= 1) s += __shfl_xor(s, m);
        float mu = s * (1.0f / 64.0f);
        float dv = a - mu;
        float qv = dv * dv;
#pragma unroll
        for (int m = 1; m < 64; m <<= 1) qv += __shfl_xor(qv, m);
        float rstd = rsqrtf(qv * (1.0f / 64.0f) + EPSL);
        float y = lrelu(dv * rstd * gg + bb);
        int nn = n0 + lnn;
        if (nn < N_AREA) h1[(size_t)b * (N_AREA * HID) + (size_t)nn * HID + lane] = y;
    }
}

// Fused conv: quad-edge gather (16 lanes x float4 per row, 4 edges per load instr) -> 64x64 GEMM -> epilogue
// EPI 0: out = leaky(.+b) + resid
// EPI 2: h3 = leaky(LN(.+b)) + resid; out = tanh(h3 @ Wf + bf)   (fuses final GEMM, no h3 round-trip)
template <int EPI>
__global__ __launch_bounds__(256, 8) void k_conv(const float* __restrict__ src, const float* __restrict__ W,
                                                 const float* __restrict__ bias, const float* __restrict__ g,
                                                 const float* __restrict__ be, const float* __restrict__ resid,
                                                 float* __restrict__ out, const int* __restrict__ offs,
                                                 const int2* __restrict__ ew, const float* __restrict__ Wf,
                                                 const float* __restrict__ bf) {
    __shared__ float a_t[64][68];  // [feat][node] for GEMM1; reused as [node][feat] for fused GEMM2
    int blk = blockIdx.x;
    int xc = blk & 7, ii = blk >> 3;
    int b = xc + 8 * (ii / NCHUNK);
    int c = ii % NCHUNK;
    int n0 = c * 64;
    int t = threadIdx.x;
    int lane = t & 63;
    int wave = __builtin_amdgcn_readfirstlane(t) >> 6;  // provably wave-uniform -> scalar offs/e
    int q = lane >> 4;        // which edge of the quad this lane handles
    int f4 = (lane & 15) * 4; // feature sub-offset within the row
    const float* sb = src + (size_t)b * (N_AREA * HID);
    int nb = n0 + wave * 16;  // first node of this wave (uniform)
    int beg = (nb < N_AREA) ? offs[nb] : 0;
    for (int j = 0; j < 16; ++j) {
        int n = nb + j;  // uniform
        float4 acc = make_float4(0.f, 0.f, 0.f, 0.f);
        float4 acc2 = make_float4(0.f, 0.f, 0.f, 0.f);
        if (n < N_AREA) {
            int end = offs[n + 1];  // s_load; beg chained from previous node
            int e = beg;
            for (; e + 7 < end; e += 8) {  // 2 independent quads (8 edges) in flight
                int2 ea = ew[e + q];
                int2 eb = ew[e + 4 + q];
                float4 va = *(const float4*)(sb + (unsigned)ea.x * HID + f4);
                float4 vb = *(const float4*)(sb + (unsigned)eb.x * HID + f4);
                float wa = __int_as_float(ea.y), wb = __int_as_float(eb.y);
                acc.x += wa * va.x; acc.y += wa * va.y; acc.z += wa * va.z; acc.w += wa * va.w;
                acc2.x += wb * vb.x; acc2.y += wb * vb.y; acc2.z += wb * vb.z; acc2.w += wb * vb.w;
            }
            if (e < end) {  // padded counts are x4: at most one remainder quad
                int2 ea = ew[e + q];
                float4 va = *(const float4*)(sb + (unsigned)ea.x * HID + f4);
                float wa = __int_as_float(ea.y);
                acc.x += wa * va.x; acc.y += wa * va.y; acc.z += wa * va.z; acc.w += wa * va.w;
            }
            beg = end;
        }
        // reduce the 4 quad-partials (lanes L, L^16, L^32, L^48 hold same features)
        acc.x += acc2.x; acc.y += acc2.y; acc.z += acc2.z; acc.w += acc2.w;
        acc.x += __shfl_xor(acc.x, 16); acc.y += __shfl_xor(acc.y, 16);
        acc.z += __shfl_xor(acc.z, 16); acc.w += __shfl_xor(acc.w, 16);
        acc.x += __shfl_xor(acc.x, 32); acc.y += __shfl_xor(acc.y, 32);
        acc.z += __shfl_xor(acc.z, 32); acc.w += __shfl_xor(acc.w, 32);
        if (q == 0) {
            int ln = wave * 16 + j;
            a_t[f4 + 0][ln] = acc.x;
            a_t[f4 + 1][ln] = acc.y;
            a_t[f4 + 2][ln] = acc.z;
            a_t[f4 + 3][ln] = acc.w;
        }
    }
    __syncthreads();
    int ty = t >> 4, tx = t & 15;
    int r0 = ty * 4, c0 = tx * 4;
    float am[4][4] = {};
#pragma unroll 4
    for (int k = 0; k < 64; ++k) {
        float4 av = *(const float4*)&a_t[k][r0];
        float4 wv = *(const float4*)(W + k * HID + c0);  // 16 KB, L1-resident, shared by all blocks
        am[0][0] += av.x * wv.x; am[0][1] += av.x * wv.y; am[0][2] += av.x * wv.z; am[0][3] += av.x * wv.w;
        am[1][0] += av.y * wv.x; am[1][1] += av.y * wv.y; am[1][2] += av.y * wv.z; am[1][3] += av.y * wv.w;
        am[2][0] += av.z * wv.x; am[2][1] += av.z * wv.y; am[2][2] += av.z * wv.z; am[2][3] += av.z * wv.w;
        am[3][0] += av.w * wv.x; am[3][1] += av.w * wv.y; am[3][2] += av.w * wv.z; am[3][3] += av.w * wv.w;
    }
    float4 bv = *(const float4*)(bias + c0);
#pragma unroll
    for (int i = 0; i < 4; ++i) {
        am[i][0] += bv.x; am[i][1] += bv.y; am[i][2] += bv.z; am[i][3] += bv.w;
    }
    if constexpr (EPI >= 1) {  // LayerNorm across 64 feats (feats live on the 16-thread tx group)
        float4 gv = *(const float4*)(g + c0);
        float4 bev = *(const float4*)(be + c0);
        float gg[4] = {gv.x, gv.y, gv.z, gv.w};
        float bb[4] = {bev.x, bev.y, bev.z, bev.w};
#pragma unroll
        for (int i = 0; i < 4; ++i) {
            float s = am[i][0] + am[i][1] + am[i][2] + am[i][3];
            float qv = am[i][0] * am[i][0] + am[i][1] * am[i][1] + am[i][2] * am[i][2] + am[i][3] * am[i][3];
#pragma unroll
            for (int m = 1; m < 16; m <<= 1) {
                s += __shfl_xor(s, m);
                qv += __shfl_xor(qv, m);
            }
            float mu = s * (1.0f / 64.0f);
            float var = qv * (1.0f / 64.0f) - mu * mu;
            float rstd = rsqrtf(var + EPSL);
#pragma unroll
            for (int j = 0; j < 4; ++j) am[i][j] = (am[i][j] - mu) * rstd * gg[j] + bb[j];
        }
    }
    const float* rb = resid + (size_t)b * (N_AREA * HID);
    float* ob = out + (size_t)b * (N_AREA * HID);
    if constexpr (EPI == 0) {
#pragma unroll
        for (int i = 0; i < 4; ++i) {
            int n = n0 + r0 + i;
            if (n < N_AREA) {
                float4 rv = *(const float4*)(rb + (size_t)n * HID + c0);
                float4 o;
                o.x = lrelu(am[i][0]) + rv.x;
                o.y = lrelu(am[i][1]) + rv.y;
                o.z = lrelu(am[i][2]) + rv.z;
                o.w = lrelu(am[i][3]) + rv.w;
                *(float4*)(ob + (size_t)n * HID + c0) = o;
            }
        }
    } else {  // EPI == 2: finish h3 in-register, stash tile to LDS, GEMM2 with Wf, tanh, store
#pragma unroll
        for (int i = 0; i < 4; ++i) {
            int n = n0 + r0 + i;
            int nc = n < N_AREA ? n : (N_AREA - 1);  // clamp OOB rows (values unused)
            float4 rv = *(const float4*)(rb + (size_t)nc * HID + c0);
            am[i][0] = lrelu(am[i][0]) + rv.x;
            am[i][1] = lrelu(am[i][1]) + rv.y;
            am[i][2] = lrelu(am[i][2]) + rv.z;
            am[i][3] = lrelu(am[i][3]) + rv.w;
        }
        __syncthreads();  // all GEMM1 reads of a_t done
        float (*h3s)[68] = a_t;  // reuse as [node][feat]
#pragma unroll
        for (int i = 0; i < 4; ++i)
            *(float4*)&h3s[r0 + i][c0] = make_float4(am[i][0], am[i][1], am[i][2], am[i][3]);
        __syncthreads();
#pragma unroll
        for (int i = 0; i < 4; ++i) { am[i][0] = 0.f; am[i][1] = 0.f; am[i][2] = 0.f; am[i][3] = 0.f; }
#pragma unroll 4
        for (int k = 0; k < 64; ++k) {
            float4 wv = *(const float4*)(Wf + k * HID + c0);
            float a0 = h3s[r0 + 0][k];  // 4 distinct addrs per wave -> broadcast, conflict-free
            float a1 = h3s[r0 + 1][k];
            float a2 = h3s[r0 + 2][k];
            float a3 = h3s[r0 + 3][k];
            am[0][0] += a0 * wv.x; am[0][1] += a0 * wv.y; am[0][2] += a0 * wv.z; am[0][3] += a0 * wv.w;
            am[1][0] += a1 * wv.x; am[1][1] += a1 * wv.y; am[1][2] += a1 * wv.z; am[1][3] += a1 * wv.w;
            am[2][0] += a2 * wv.x; am[2][1] += a2 * wv.y; am[2][2] += a2 * wv.z; am[2][3] += a2 * wv.w;
            am[3][0] += a3 * wv.x; am[3][1] += a3 * wv.y; am[3][2] += a3 * wv.z; am[3][3] += a3 * wv.w;
        }
        float4 bfv = *(const float4*)(bf + c0);
#pragma unroll
        for (int i = 0; i < 4; ++i) {
            int n = n0 + r0 + i;
            if (n < N_AREA) {
                float4 o;
                o.x = tanh_fast(am[i][0] + bfv.x);
                o.y = tanh_fast(am[i][1] + bfv.y);
                o.z = tanh_fast(am[i][2] + bfv.z);
                o.w = tanh_fast(am[i][3] + bfv.w);
                *(float4*)(ob + (size_t)n * HID + c0) = o;
            }
        }
    }
}

extern "C" void kernel_launch(void* const* d_in, const int* in_sizes, int n_in,
                              void* d_out, int out_size, void* d_ws, size_t ws_size,
                              hipStream_t stream) {
    const float* state = (const float*)d_in[0];
    const int* ei = (const int*)d_in[1];
    const int E = in_sizes[1] / 2;
    const float* W1 = (const float*)d_in[5];
    const float* b1 = (const float*)d_in[6];
    const float* W2 = (const float*)d_in[7];
    const float* b2 = (const float*)d_in[8];
    const float* W3 = (const float*)d_in[9];
    const float* b3 = (const float*)d_in[10];
    const float* g1 = (const float*)d_in[11];
    const float* be1 = (const float*)d_in[12];
    const float* g3 = (const float*)d_in[13];
    const float* be3 = (const float*)d_in[14];
    const float* Wf = (const float*)d_in[15];
    const float* bf = (const float*)d_in[16];
    float* out = (float*)d_out;

    uint8_t* base = (uint8_t*)d_ws;
    size_t off = 0;
    auto carve = [&](size_t bytes) {
        void* p = base + off;
        off = (off + bytes + 255) & ~(size_t)255;
        return p;
    };
    float* dinv = (float*)carve(N_AREA * 4);
    int* counts = (int*)carve(N_AREA * 4);
    int* offsets = (int*)carve((N_AREA + 1) * 4);
    int* cursor = (int*)carve(N_AREA * 4);
    int2* ew = (int2*)carve(((size_t)E + 4 * N_AREA) * 8);  // padded edge list
    float* h1 = (float*)carve((size_t)BATCH * N_AREA * HID * 4);
    float* h2 = (float*)carve((size_t)BATCH * N_AREA * HID * 4);

    const int GRID = 8 * NCHUNK * (BATCH / 8);  // 10048

    k_zero<<<(N_AREA + 255) / 256, 256, 0, stream>>>(counts, N_AREA);
    k_hist<<<(E + 255) / 256, 256, 0, stream>>>(ei + E, counts, E);
    k_scan<<<1, 1024, 0, stream>>>(counts, offsets, cursor, dinv, ew);
    k_scatter<<<(E + 255) / 256, 256, 0, stream>>>(ei, dinv, cursor, ew, E);

    k_conv1<<<GRID, 256, 0, stream>>>(state, W1, b1, g1, be1, h1, offsets, ew);
    k_conv<0><<<GRID, 256, 0, stream>>>(h1, W2, b2, nullptr, nullptr, h1, h2, offsets, ew, nullptr, nullptr);
    k_conv<2><<<GRID, 256, 0, stream>>>(h2, W3, b3, g3, be3, h1, out, offsets, ew, Wf, bf);
}